// Round 19
// baseline (20.817 us; speedup 1.0000x reference)
//
#include <hip/hip_runtime.h>

#define PN 131072
#define PH 1024
#define G 96
#define GPTS (G * G)           // 9216
#define GLO   (-4.25f)
#define GSTEP (8.5f / 95.0f)
#define GINV  (95.0f / 8.5f)
#define XMAX  4.2f             // beyond this -> direct-eval fallback
#define SCF   2.8853900817779268f          // 2*log2(e)
#define SCGSTEP (SCF * GSTEP)
#define SCGLO   (SCF * GLO)

// Catmull-Rom weights for t in [0,1)
static __device__ __forceinline__ void cr_w(float t, float w[4]) {
    w[0] = t * (-0.5f + t * (1.0f - 0.5f * t));
    w[1] = 1.0f + t * t * (-2.5f + 1.5f * t);
    w[2] = t * (0.5f + t * (2.0f - 1.5f * t));
    w[3] = t * t * (-0.5f + 0.5f * t);
}

// ===== K1: full table eval, one dispatch ====================================
// 144 blocks x 1024 thr (16 waves). Wave wv owns the wave-uniform 64-h chunk
// [wv*64, wv*64+64) streamed from GLOBAL (scalarizable s_load). lane = grid
// point (64/block). 16-wave LDS reduce covers all 1024 h; final grid written
// directly (no reduce dispatch).
__global__ __launch_bounds__(1024) void eval_kernel(const float4* __restrict__ W1f4,
                                                    const float2* __restrict__ b1f2,
                                                    const float2* __restrict__ w2f2,
                                                    const float* __restrict__ b2p,
                                                    float4* __restrict__ grid) {
    const int tid  = threadIdx.x;
    const int lane = tid & 63, wv = tid >> 6;          // 16 waves
    const int bid  = blockIdx.x;
    const int chunk = __builtin_amdgcn_readfirstlane(wv);   // 0..15, 64 h each

    const int p  = bid * 64 + lane;                    // grid point 0..9215
    const int iy = p / G;
    const int ix = p - iy * G;
    const float x0s = __builtin_fmaf((float)ix, SCGSTEP, SCGLO);   // SC-scaled
    const float x1s = __builtin_fmaf((float)iy, SCGSTEP, SCGLO);

    // chunk covers 64 h = 32 pairs
    const float4* __restrict__ W = W1f4 + chunk * 32;  // {w10a,w11a,w10b,w11b}
    const float2* __restrict__ B = b1f2 + chunk * 32;
    const float2* __restrict__ V = w2f2 + chunk * 32;

    float aT = 0.f, a1 = 0.f, a2 = 0.f, aD = 0.f;

    #pragma unroll 4
    for (int j = 0; j < 32; ++j) {
        const float4 w = W[j];
        const float2 b = B[j];
        const float2 v = V[j];

        float zsa = __builtin_fmaf(x0s, w.x, __builtin_fmaf(x1s, w.y, b.x * SCF));
        float zsb = __builtin_fmaf(x0s, w.z, __builtin_fmaf(x1s, w.w, b.y * SCF));
        zsa = fminf(zsa, 40.0f);
        zsb = fminf(zsb, 40.0f);
        const float ea = __builtin_amdgcn_exp2f(zsa);       // e^{2z}
        const float eb = __builtin_amdgcn_exp2f(zsb);
        const float da = ea + 1.0f, db = eb + 1.0f;
        const float rab = __builtin_amdgcn_rcpf(da * db);   // shared rcp
        const float ra = rab * db, rb = rab * da;           // 1/(1+e^{2z})
        const float ta = __builtin_fmaf(-2.0f, ra, 1.0f);   // tanh
        const float tb = __builtin_fmaf(-2.0f, rb, 1.0f);
        const float ua = __builtin_fmaf(-ra, ra, ra);       // r - r^2 = q/4
        const float ub = __builtin_fmaf(-rb, rb, rb);
        const float rua = ra * ua, rub = rb * ub;
        const float tua = __builtin_fmaf(-2.0f, rua, ua);   // t*u
        const float tub = __builtin_fmaf(-2.0f, rub, ub);

        const float uw2a = ua * v.x,  uw2b = ub * v.y;      // u*w2
        const float tw2a = tua * v.x, tw2b = tub * v.y;     // t*u*w2

        aT = __builtin_fmaf(ta, v.x, aT);                   // sum t*w2
        aT = __builtin_fmaf(tb, v.y, aT);
        a1 = __builtin_fmaf(uw2a, w.x, a1);                 // * w10
        a1 = __builtin_fmaf(uw2b, w.z, a1);
        a2 = __builtin_fmaf(uw2a, w.y, a2);                 // * w11
        a2 = __builtin_fmaf(uw2b, w.w, a2);
        aD = __builtin_fmaf(tw2a * w.y, w.y, aD);           // * w11^2
        aD = __builtin_fmaf(tw2b * w.w, w.w, aD);
    }

    // reduce the block's 16 waves (covers all 1024 h)
    __shared__ float4 red[16][64];
    red[wv][lane] = make_float4(aT, a1, a2, aD);
    __syncthreads();
    if (tid < 64) {
        float4 s = red[0][tid];
        #pragma unroll
        for (int w = 1; w < 16; ++w) {
            const float4 o = red[w][tid];
            s.x += o.x; s.y += o.y; s.z += o.z; s.w += o.w;
        }
        // f = sum t*w2 + b2 ; ft = 4*sum u*w10*w2 ; fx = 4*sum u*w11*w2 ;
        // fxx = -8*sum t*u*w11^2*w2
        grid[bid * 64 + tid] = make_float4(s.x + b2p[0], 4.0f * s.y,
                                           4.0f * s.z, -8.0f * s.w);
    }
}

// ===== K2: bicubic interp, 2 threads/row + cooperative fallback =============
__global__ __launch_bounds__(256) void interp_kernel(const float2* __restrict__ x2,
                                                     const float4* __restrict__ grid,
                                                     const float* __restrict__ W1,
                                                     const float* __restrict__ b1,
                                                     const float* __restrict__ w2,
                                                     const float* __restrict__ b2p,
                                                     float* __restrict__ out) {
    const int g = blockIdx.x * 256 + threadIdx.x;
    const int row = g >> 1;
    const int half = g & 1;
    const float2 xv = x2[row];

    float u = (xv.x - GLO) * GINV;
    float v = (xv.y - GLO) * GINV;
    u = fminf(fmaxf(u, 0.0f), (float)(G - 1) - 1e-3f);
    v = fminf(fmaxf(v, 0.0f), (float)(G - 1) - 1e-3f);
    int iu = (int)u;  iu = iu > G - 2 ? G - 2 : iu;
    int iv = (int)v;  iv = iv > G - 2 ? G - 2 : iv;
    const float fu = u - (float)iu;
    const float fv = v - (float)iv;

    float wu[4], wv_[4];
    cr_w(fu, wu);
    cr_w(fv, wv_);

    const int ju0 = iu - 1 < 0 ? 0 : iu - 1;
    const int ju3 = iu + 2 > G - 1 ? G - 1 : iu + 2;
    const int jv0 = iv - 1 < 0 ? 0 : iv - 1;
    const int jv3 = iv + 2 > G - 1 ? G - 1 : iv + 2;
    const int rowsIdx[4] = { jv0 * G, iv * G, (iv + 1) * G, jv3 * G };

    float af = 0.f, at = 0.f, ax = 0.f, axx = 0.f;
    #pragma unroll
    for (int rr = 0; rr < 2; ++rr) {
        const int r = 2 * half + rr;
        const int base = rowsIdx[r];
        const float4 g0 = grid[base + ju0];
        const float4 g1 = grid[base + iu];
        const float4 g2 = grid[base + iu + 1];
        const float4 g3 = grid[base + ju3];
        const float rf  = wu[0] * g0.x + wu[1] * g1.x + wu[2] * g2.x + wu[3] * g3.x;
        const float rt  = wu[0] * g0.y + wu[1] * g1.y + wu[2] * g2.y + wu[3] * g3.y;
        const float rx  = wu[0] * g0.z + wu[1] * g1.z + wu[2] * g2.z + wu[3] * g3.z;
        const float rxx = wu[0] * g0.w + wu[1] * g1.w + wu[2] * g2.w + wu[3] * g3.w;
        af  = __builtin_fmaf(wv_[r], rf,  af);
        at  = __builtin_fmaf(wv_[r], rt,  at);
        ax  = __builtin_fmaf(wv_[r], rx,  ax);
        axx = __builtin_fmaf(wv_[r], rxx, axx);
    }
    af  += __shfl_xor(af,  1, 64);
    at  += __shfl_xor(at,  1, 64);
    ax  += __shfl_xor(ax,  1, 64);
    axx += __shfl_xor(axx, 1, 64);

    // fallback: exact direct eval for out-of-range rows (cooperative, rare)
    const bool outl = ((fabsf(xv.x) > XMAX) || (fabsf(xv.y) > XMAX)) && (half == 0);
    unsigned long long mball = __ballot(outl);
    if (mball) {
        const int lane = threadIdx.x & 63;
        const float b2v = b2p[0];
        while (mball) {
            const int l = (int)__ffsll((unsigned long long)mball) - 1;
            mball &= mball - 1;
            const float fx0 = __shfl(xv.x, l, 64);
            const float fx1 = __shfl(xv.y, l, 64);
            float s_f = 0.f, s1 = 0.f, s2 = 0.f, s3 = 0.f, s4 = 0.f;
            for (int k = 0; k < 16; ++k) {
                const int h = lane * 16 + k;
                const float w10 = W1[2 * h], w11 = W1[2 * h + 1];
                const float b1h = b1[h], w2h = w2[h];
                float zs = SCF * __builtin_fmaf(fx0, w10, __builtin_fmaf(fx1, w11, b1h));
                zs = fminf(zs, 40.0f);
                const float e = __builtin_amdgcn_exp2f(zs);
                const float r = __builtin_amdgcn_rcpf(e + 1.0f);
                const float t = __builtin_fmaf(-2.0f, r, 1.0f);
                const float uq = __builtin_fmaf(-r, r, r);
                const float ru = r * uq;
                const float c1 = w10 * w2h, c2 = w11 * w2h, c3 = w11 * c2;
                s_f += t * w2h;
                s1 = __builtin_fmaf(uq, c1, s1);
                s2 = __builtin_fmaf(uq, c2, s2);
                s3 = __builtin_fmaf(uq, c3, s3);
                s4 = __builtin_fmaf(ru, c3, s4);
            }
            #pragma unroll
            for (int m = 32; m >= 1; m >>= 1) {
                s_f += __shfl_xor(s_f, m, 64);
                s1  += __shfl_xor(s1,  m, 64);
                s2  += __shfl_xor(s2,  m, 64);
                s3  += __shfl_xor(s3,  m, 64);
                s4  += __shfl_xor(s4,  m, 64);
            }
            if (lane == l) {
                af  = s_f + b2v;
                at  = 4.0f * s1;
                ax  = 4.0f * s2;
                axx = -8.0f * (s3 - 2.0f * s4);
            }
        }
    }

    if (half == 0) {
        const float x1 = xv.y;
        const float pde = __builtin_fmaf(0.5f * x1, x1, at)
                        + 0.5f * axx
                        + 0.5f * x1 * ax
                        - 0.069444444444444445f * ax * ax;
        out[row] = af;
        out[PN + row] = pde;
    }
}

extern "C" void kernel_launch(void* const* d_in, const int* in_sizes, int n_in,
                              void* d_out, int out_size, void* d_ws, size_t ws_size,
                              hipStream_t stream) {
    const float* x  = (const float*)d_in[0];
    const float* W1 = (const float*)d_in[1];
    const float* b1 = (const float*)d_in[2];
    const float* w2 = (const float*)d_in[3];
    const float* b2 = (const float*)d_in[4];
    float* out = (float*)d_out;

    float4* grid = (float4*)d_ws;                 // GPTS float4 = 147 KiB

    eval_kernel<<<GPTS / 64, 1024, 0, stream>>>((const float4*)W1, (const float2*)b1,
                                                (const float2*)w2, b2, grid);
    interp_kernel<<<PN * 2 / 256, 256, 0, stream>>>((const float2*)x, grid,
                                                    W1, b1, w2, b2, out);
}

// Round 20
// 19.701 us; speedup vs baseline: 1.0567x; 1.0567x over previous
//
#include <hip/hip_runtime.h>

#define PN 131072
#define PH 1024
#define G 96
#define GPTS (G * G)           // 9216
#define NPB (GPTS / 64)        // 144 point-blocks
#define GLO   (-4.25f)
#define GSTEP (8.5f / 95.0f)
#define GINV  (95.0f / 8.5f)
#define XMAX  4.2f             // beyond this -> direct-eval fallback
#define SCF   2.8853900817779268f          // 2*log2(e)
#define SCGSTEP (SCF * GSTEP)
#define SCGLO   (SCF * GLO)

// Catmull-Rom weights for t in [0,1)
static __device__ __forceinline__ void cr_w(float t, float w[4]) {
    w[0] = t * (-0.5f + t * (1.0f - 0.5f * t));
    w[1] = 1.0f + t * t * (-2.5f + 1.5f * t);
    w[2] = t * (0.5f + t * (2.0f - 1.5f * t));
    w[3] = t * t * (-0.5f + 0.5f * t);
}

// ===== K1a: partial table eval ==============================================
// 576 blocks x 512 thr (8 waves): block = (pb 0..143) x (hb 0..3).
// Wave owns a wave-uniform 32-h chunk streamed from GLOBAL (scalarizable).
// lane = grid point.
__global__ __launch_bounds__(512, 8) void eval_part_kernel(const float4* __restrict__ W1f4,
                                                           const float2* __restrict__ b1f2,
                                                           const float2* __restrict__ w2f2,
                                                           float4* __restrict__ part) {
    const int tid  = threadIdx.x;
    const int lane = tid & 63, wv = tid >> 6;          // 8 waves
    const int bid  = blockIdx.x;
    const int hb   = bid & 3;                          // h-block 0..3
    const int pb   = bid >> 2;                         // point-block 0..143
    const int chunk = __builtin_amdgcn_readfirstlane(hb * 8 + wv);  // 0..31

    const int p  = pb * 64 + lane;                     // grid point 0..9215
    const int iy = p / G;
    const int ix = p - iy * G;
    const float x0s = __builtin_fmaf((float)ix, SCGSTEP, SCGLO);   // SC-scaled
    const float x1s = __builtin_fmaf((float)iy, SCGSTEP, SCGLO);

    // chunk covers 32 h = 16 pairs
    const float4* __restrict__ W = W1f4 + chunk * 16;  // {w10a,w11a,w10b,w11b}
    const float2* __restrict__ B = b1f2 + chunk * 16;
    const float2* __restrict__ V = w2f2 + chunk * 16;

    float aT = 0.f, a1 = 0.f, a2 = 0.f, aD = 0.f;

    #pragma unroll 4
    for (int j = 0; j < 16; ++j) {
        const float4 w = W[j];
        const float2 b = B[j];
        const float2 v = V[j];

        float zsa = __builtin_fmaf(x0s, w.x, __builtin_fmaf(x1s, w.y, b.x * SCF));
        float zsb = __builtin_fmaf(x0s, w.z, __builtin_fmaf(x1s, w.w, b.y * SCF));
        zsa = fminf(zsa, 40.0f);
        zsb = fminf(zsb, 40.0f);
        const float ea = __builtin_amdgcn_exp2f(zsa);       // e^{2z}
        const float eb = __builtin_amdgcn_exp2f(zsb);
        const float da = ea + 1.0f, db = eb + 1.0f;
        const float rab = __builtin_amdgcn_rcpf(da * db);   // shared rcp
        const float ra = rab * db, rb = rab * da;           // 1/(1+e^{2z})
        const float ta = __builtin_fmaf(-2.0f, ra, 1.0f);   // tanh
        const float tb = __builtin_fmaf(-2.0f, rb, 1.0f);
        const float ua = __builtin_fmaf(-ra, ra, ra);       // r - r^2 = q/4
        const float ub = __builtin_fmaf(-rb, rb, rb);
        const float rua = ra * ua, rub = rb * ub;
        const float tua = __builtin_fmaf(-2.0f, rua, ua);   // t*u
        const float tub = __builtin_fmaf(-2.0f, rub, ub);

        const float uw2a = ua * v.x,  uw2b = ub * v.y;      // u*w2
        const float tw2a = tua * v.x, tw2b = tub * v.y;     // t*u*w2

        aT = __builtin_fmaf(ta, v.x, aT);                   // sum t*w2
        aT = __builtin_fmaf(tb, v.y, aT);
        a1 = __builtin_fmaf(uw2a, w.x, a1);                 // * w10
        a1 = __builtin_fmaf(uw2b, w.z, a1);
        a2 = __builtin_fmaf(uw2a, w.y, a2);                 // * w11
        a2 = __builtin_fmaf(uw2b, w.w, a2);
        aD = __builtin_fmaf(tw2a * w.y, w.y, aD);           // * w11^2
        aD = __builtin_fmaf(tw2b * w.w, w.w, aD);
    }

    // reduce the block's 8 waves
    __shared__ float4 red[8][64];
    if (wv != 0) red[wv][lane] = make_float4(aT, a1, a2, aD);
    __syncthreads();
    if (wv == 0) {
        float sT = aT, s1 = a1, s2 = a2, sD = aD;
        #pragma unroll
        for (int w = 1; w < 8; ++w) {
            const float4 o = red[w][lane];
            sT += o.x; s1 += o.y; s2 += o.z; sD += o.w;
        }
        part[hb * GPTS + p] = make_float4(sT, s1, s2, sD);
    }
}

// ===== K1b: combine 4 h-block partials, finalize fields =====================
__global__ __launch_bounds__(256) void reduce_kernel(const float4* __restrict__ part,
                                                     const float* __restrict__ b2p,
                                                     float4* __restrict__ grid) {
    const int pt = blockIdx.x * 256 + threadIdx.x;
    float4 s = part[pt];
    #pragma unroll
    for (int k = 1; k < 4; ++k) {
        const float4 o = part[k * GPTS + pt];
        s.x += o.x; s.y += o.y; s.z += o.z; s.w += o.w;
    }
    // f = sum t*w2 + b2 ; df_dt = 4*sum u*w10*w2 ; df_dx = 4*sum u*w11*w2 ;
    // df_dxdx = -8*sum t*u*w11^2*w2
    grid[pt] = make_float4(s.x + b2p[0], 4.0f * s.y, 4.0f * s.z, -8.0f * s.w);
}

// ===== K2: bicubic interp, 2 threads/row + cooperative fallback =============
__global__ __launch_bounds__(256) void interp_kernel(const float2* __restrict__ x2,
                                                     const float4* __restrict__ grid,
                                                     const float* __restrict__ W1,
                                                     const float* __restrict__ b1,
                                                     const float* __restrict__ w2,
                                                     const float* __restrict__ b2p,
                                                     float* __restrict__ out) {
    const int g = blockIdx.x * 256 + threadIdx.x;
    const int row = g >> 1;
    const int half = g & 1;
    const float2 xv = x2[row];

    float u = (xv.x - GLO) * GINV;
    float v = (xv.y - GLO) * GINV;
    u = fminf(fmaxf(u, 0.0f), (float)(G - 1) - 1e-3f);
    v = fminf(fmaxf(v, 0.0f), (float)(G - 1) - 1e-3f);
    int iu = (int)u;  iu = iu > G - 2 ? G - 2 : iu;
    int iv = (int)v;  iv = iv > G - 2 ? G - 2 : iv;
    const float fu = u - (float)iu;
    const float fv = v - (float)iv;

    float wu[4], wv_[4];
    cr_w(fu, wu);
    cr_w(fv, wv_);

    const int ju0 = iu - 1 < 0 ? 0 : iu - 1;
    const int ju3 = iu + 2 > G - 1 ? G - 1 : iu + 2;
    const int jv0 = iv - 1 < 0 ? 0 : iv - 1;
    const int jv3 = iv + 2 > G - 1 ? G - 1 : iv + 2;
    const int rowsIdx[4] = { jv0 * G, iv * G, (iv + 1) * G, jv3 * G };

    float af = 0.f, at = 0.f, ax = 0.f, axx = 0.f;
    #pragma unroll
    for (int rr = 0; rr < 2; ++rr) {
        const int r = 2 * half + rr;
        const int base = rowsIdx[r];
        const float4 g0 = grid[base + ju0];
        const float4 g1 = grid[base + iu];
        const float4 g2 = grid[base + iu + 1];
        const float4 g3 = grid[base + ju3];
        const float rf  = wu[0] * g0.x + wu[1] * g1.x + wu[2] * g2.x + wu[3] * g3.x;
        const float rt  = wu[0] * g0.y + wu[1] * g1.y + wu[2] * g2.y + wu[3] * g3.y;
        const float rx  = wu[0] * g0.z + wu[1] * g1.z + wu[2] * g2.z + wu[3] * g3.z;
        const float rxx = wu[0] * g0.w + wu[1] * g1.w + wu[2] * g2.w + wu[3] * g3.w;
        af  = __builtin_fmaf(wv_[r], rf,  af);
        at  = __builtin_fmaf(wv_[r], rt,  at);
        ax  = __builtin_fmaf(wv_[r], rx,  ax);
        axx = __builtin_fmaf(wv_[r], rxx, axx);
    }
    af  += __shfl_xor(af,  1, 64);
    at  += __shfl_xor(at,  1, 64);
    ax  += __shfl_xor(ax,  1, 64);
    axx += __shfl_xor(axx, 1, 64);

    // fallback: exact direct eval for out-of-range rows (cooperative, rare)
    const bool outl = ((fabsf(xv.x) > XMAX) || (fabsf(xv.y) > XMAX)) && (half == 0);
    unsigned long long mball = __ballot(outl);
    if (mball) {
        const int lane = threadIdx.x & 63;
        const float b2v = b2p[0];
        while (mball) {
            const int l = (int)__ffsll((unsigned long long)mball) - 1;
            mball &= mball - 1;
            const float fx0 = __shfl(xv.x, l, 64);
            const float fx1 = __shfl(xv.y, l, 64);
            float s_f = 0.f, s1 = 0.f, s2 = 0.f, s3 = 0.f, s4 = 0.f;
            for (int k = 0; k < 16; ++k) {
                const int h = lane * 16 + k;
                const float w10 = W1[2 * h], w11 = W1[2 * h + 1];
                const float b1h = b1[h], w2h = w2[h];
                float zs = SCF * __builtin_fmaf(fx0, w10, __builtin_fmaf(fx1, w11, b1h));
                zs = fminf(zs, 40.0f);
                const float e = __builtin_amdgcn_exp2f(zs);
                const float r = __builtin_amdgcn_rcpf(e + 1.0f);
                const float t = __builtin_fmaf(-2.0f, r, 1.0f);
                const float uq = __builtin_fmaf(-r, r, r);
                const float ru = r * uq;
                const float c1 = w10 * w2h, c2 = w11 * w2h, c3 = w11 * c2;
                s_f += t * w2h;
                s1 = __builtin_fmaf(uq, c1, s1);
                s2 = __builtin_fmaf(uq, c2, s2);
                s3 = __builtin_fmaf(uq, c3, s3);
                s4 = __builtin_fmaf(ru, c3, s4);
            }
            #pragma unroll
            for (int m = 32; m >= 1; m >>= 1) {
                s_f += __shfl_xor(s_f, m, 64);
                s1  += __shfl_xor(s1,  m, 64);
                s2  += __shfl_xor(s2,  m, 64);
                s3  += __shfl_xor(s3,  m, 64);
                s4  += __shfl_xor(s4,  m, 64);
            }
            if (lane == l) {
                af  = s_f + b2v;
                at  = 4.0f * s1;
                ax  = 4.0f * s2;
                axx = -8.0f * (s3 - 2.0f * s4);
            }
        }
    }

    if (half == 0) {
        const float x1 = xv.y;
        const float pde = __builtin_fmaf(0.5f * x1, x1, at)
                        + 0.5f * axx
                        + 0.5f * x1 * ax
                        - 0.069444444444444445f * ax * ax;
        out[row] = af;
        out[PN + row] = pde;
    }
}

extern "C" void kernel_launch(void* const* d_in, const int* in_sizes, int n_in,
                              void* d_out, int out_size, void* d_ws, size_t ws_size,
                              hipStream_t stream) {
    const float* x  = (const float*)d_in[0];
    const float* W1 = (const float*)d_in[1];
    const float* b1 = (const float*)d_in[2];
    const float* w2 = (const float*)d_in[3];
    const float* b2 = (const float*)d_in[4];
    float* out = (float*)d_out;

    float4* grid = (float4*)d_ws;                 // GPTS float4
    float4* part = grid + GPTS;                   // 4*GPTS float4

    eval_part_kernel<<<NPB * 4, 512, 0, stream>>>((const float4*)W1, (const float2*)b1,
                                                  (const float2*)w2, part);
    reduce_kernel<<<GPTS / 256, 256, 0, stream>>>(part, b2, grid);
    interp_kernel<<<PN * 2 / 256, 256, 0, stream>>>((const float2*)x, grid,
                                                    W1, b1, w2, b2, out);
}